// Round 1
// baseline (196.070 us; speedup 1.0000x reference)
//
#include <hip/hip_runtime.h>
#include <hip/hip_bf16.h>
#include <stdint.h>

#define B_ROWS 16384   // batch rows (M)
#define C_ROWS 2048    // class rows (N)
#define D_FULL 512     // input feature dim
#define KP     512     // padded K (511 real + 1 zero col)

#define BM 256
#define BN 256
#define BK 32          // 16 K-tiles, ring-4 LDS, prefetch distance 3

typedef __attribute__((ext_vector_type(8))) short bf16x8;
typedef __attribute__((ext_vector_type(4))) float f32x4;

typedef __attribute__((address_space(1))) void glb_void;
typedef __attribute__((address_space(3))) void lds_void;

// async global->LDS, 16B per lane; LDS dest = wave-uniform base + lane*16
__device__ __forceinline__ void gld16(const void* g, void* l) {
    __builtin_amdgcn_global_load_lds((glb_void*)(uintptr_t)g,
                                     (lds_void*)(uintptr_t)l, 16, 0, 0);
}

#define WAITV8 asm volatile("s_waitcnt vmcnt(8)" ::: "memory")
#define WAITV4 asm volatile("s_waitcnt vmcnt(4)" ::: "memory")
#define WAITV0 asm volatile("s_waitcnt vmcnt(0)" ::: "memory")
#define WAITL  asm volatile("s_waitcnt lgkmcnt(0)" ::: "memory")
#define SBAR   __builtin_amdgcn_s_barrier()
#define SCHEDB __builtin_amdgcn_sched_barrier(0)

// ---------------------------------------------------------------------------
// Prep: per row, dst[k] = bf16(src[k+1]) for k=0..510, dst[511]=0;
// norm = sqrt(1 + sum(src[1..511]^2)).
// One wave per row: lane l loads src[8l..8l+7] as 2x float4 (aligned,
// coalesced), gets src[8l+8] from lane l+1 via shfl, packs 8 bf16 -> one
// 16B store. No LDS, no syncthreads. 4 rows per 256-thread block.
// ---------------------------------------------------------------------------
__global__ __launch_bounds__(256) void prep_kernel(
    const float* __restrict__ x, const float* __restrict__ pts,
    unsigned short* __restrict__ Abf, unsigned short* __restrict__ Bbf,
    float* __restrict__ xn, float* __restrict__ pn)
{
    const int wave = threadIdx.x >> 6;
    const int l    = threadIdx.x & 63;
    const int row  = blockIdx.x * 4 + wave;

    const float* src;
    unsigned short* dst;
    float* nrm;
    if (row < B_ROWS) {
        src = x + (size_t)row * D_FULL;
        dst = Abf + (size_t)row * KP;
        nrm = xn + row;
    } else {
        const int r = row - B_ROWS;
        src = pts + (size_t)r * D_FULL;
        dst = Bbf + (size_t)r * KP;
        nrm = pn + r;
    }

    const float4 a = *(const float4*)&src[8 * l];
    const float4 b = *(const float4*)&src[8 * l + 4];
    float nx = __shfl_down(a.x, 1);         // src[8l+8] from lane l+1
    if (l == 63) nx = 0.0f;                 // src[512] -> pad 0 (k==511)

    float v[8] = {a.y, a.z, a.w, b.x, b.y, b.z, b.w, nx};
    float ss = 0.0f;
    union { unsigned short us[8]; uint4 q; } pk;
    #pragma unroll
    for (int j = 0; j < 8; ++j) {
        ss += v[j] * v[j];
        __hip_bfloat16 h = __float2bfloat16(v[j]);
        pk.us[j] = *(unsigned short*)&h;
    }
    *(uint4*)&dst[8 * l] = pk.q;

    #pragma unroll
    for (int off = 32; off > 0; off >>= 1) ss += __shfl_down(ss, off);
    if (l == 0) nrm[0] = sqrtf(1.0f + ss);
}

// ---------------------------------------------------------------------------
// GEMM: C[m][n] = sum_k A[m][k]*B[n][k], both K-major bf16.
// 256x256 tile, 512 threads = 8 waves (2M x 4N); each wave owns 128x64 out
// (8x4 frags of 16x16, via mfma_f32_16x16x32_bf16, 1 kk-step per K-tile).
//
// LDS: ring of 4 K-tile slots (BK=32): per slot A 16KB + B 16KB -> 128 KiB.
// While computing K-tile t (slot t&3), stage K-tile t+3 (slot (t+3)&3 ==
// (t-1)&3, whose reads finished before this tile's top barrier) -> the LDS
// write-landing hazard is structurally impossible; the ONLY waits are
// counted vmcnt(8) at tile tops (drains the 3-tiles-old set), never 0 in
// the main loop. 2 phases/K-tile {ds_read subtile + 2 gld16 + bar + lgkm +
// 16 MFMA + bar}, setprio(1) around MFMA clusters (T5).
//
// LDS layout (both-sides swizzle, same bank profile as the round-2 verified
// 128B-row scheme): rows stored as PAIRS -> 128B super-rows of 8 16B chunks;
// chunk c of row r lives at slot u = ((c<<1)|(r&1)) ^ ((r>>1)&7). Staged via
// pre-swizzled per-lane GLOBAL source + linear LDS dest (gld16 constraint);
// fragment ds_read_b128s land 2 lanes/bank (free).
//
// K accumulation order (32-wide windows, ascending) is bit-identical to the
// previous verified kernel.
// Epilogue: out = -arccosh(max(x0[m]*p0[n] - acc, 1+eps))
// ---------------------------------------------------------------------------
__global__ __launch_bounds__(512, 2) void gemm_kernel(
    const unsigned short* __restrict__ A,   // [B_ROWS][KP] bf16
    const unsigned short* __restrict__ Bm,  // [C_ROWS][KP] bf16
    const float* __restrict__ xn, const float* __restrict__ pn,
    float* __restrict__ out)
{
    __shared__ unsigned short As[4][8192];   // 4 x 16 KB  (256 rows x 32)
    __shared__ unsigned short Bs[4][8192];   // 4 x 16 KB

    const int tid  = threadIdx.x;
    const int wave = tid >> 6;
    const int lane = tid & 63;
    const int wm   = wave >> 2;        // 0..1  (M half: 128 rows)
    const int wn   = wave & 3;         // 0..3  (N quarter: 64 cols)
    const int lrow = lane & 15;
    const int quad = lane >> 4;        // 0..3

    const int bm0 = blockIdx.x * BM;
    const int bn0 = blockIdx.y * BN;

    // ---- staging mapping (per 128-row unit; 512 lanes x 16B = 8 KB) ----
    // lane writes LDS byte tid*16 = super-row P=(tid>>3), chunk-slot u=tid&7.
    // inverse swizzle: v = u ^ (P&7); global chunk c = v>>1, row parity b=v&1.
    const int P  = tid >> 3;
    const int u  = tid & 7;
    const int v  = u ^ (P & 7);
    const int sc = (v >> 1) << 3;            // chunk -> short offset
    const int rb = 2 * P + (v & 1);          // row within unit, 0..127

    const unsigned short* gA0 = A  + (size_t)(bm0 + rb) * KP + sc;
    const unsigned short* gA1 = gA0 + (size_t)128 * KP;
    const unsigned short* gB0 = Bm + (size_t)(bn0 + rb) * KP + sc;
    const unsigned short* gB1 = gB0 + (size_t)128 * KP;

    // prologue: stage K-tiles 0,1,2 into slots 0,1,2 (A,A,B,B per tile)
    #pragma unroll
    for (int t = 0; t < 3; ++t) {
        gld16(gA0 + t * BK, &As[t][wave * 512]);
        gld16(gA1 + t * BK, &As[t][4096 + wave * 512]);
        gld16(gB0 + t * BK, &Bs[t][wave * 512]);
        gld16(gB1 + t * BK, &Bs[t][4096 + wave * 512]);
    }

    // ---- fragment read offsets (shorts) ----
    // chunk-slot for (row=..+lrow, c=quad): ((quad<<1)|(lrow&1)) ^ (lrow>>1)
    const int ccs  = (((quad << 1) | (lrow & 1)) ^ (lrow >> 1)) << 3;
    const int aoff = (wm * 64 + (lrow >> 1)) * 64 + ccs;   // + mi*512
    const int boff = (wn * 32 + (lrow >> 1)) * 64 + ccs;   // + ni*512

    f32x4 acc[8][4] = {};

    #pragma unroll
    for (int t = 0; t < KP / BK; ++t) {
        const int s  = t & 3;
        const int ps = (t + 3) & 3;

        // wait for own contributions to K-tile t (issued 3 tiles ago);
        // K-tiles t+1,t+2 (8 loads) stay in flight.
        if (t <= 13)      WAITV8;
        else if (t == 14) WAITV4;
        else              WAITV0;
        SBAR; SCHEDB;

        // ---------------- phase A: mi 0..3 x ni 0..3 ----------------
        bf16x8 af[4], bfr[4];
        #pragma unroll
        for (int mi = 0; mi < 4; ++mi)
            af[mi] = *(const bf16x8*)&As[s][aoff + mi * 512];
        #pragma unroll
        for (int ni = 0; ni < 4; ++ni)
            bfr[ni] = *(const bf16x8*)&Bs[s][boff + ni * 512];
        if (t + 3 < KP / BK) {
            gld16(gA0 + (t + 3) * BK, &As[ps][wave * 512]);
            gld16(gA1 + (t + 3) * BK, &As[ps][4096 + wave * 512]);
        }
        SBAR;
        WAITL; SCHEDB;
        __builtin_amdgcn_s_setprio(1);
        #pragma unroll
        for (int mi = 0; mi < 4; ++mi)
            #pragma unroll
            for (int ni = 0; ni < 4; ++ni)
                acc[mi][ni] = __builtin_amdgcn_mfma_f32_16x16x32_bf16(
                    af[mi], bfr[ni], acc[mi][ni], 0, 0, 0);
        __builtin_amdgcn_s_setprio(0);
        SBAR;

        // ---------------- phase B: mi 4..7 x ni 0..3 ----------------
        #pragma unroll
        for (int mi = 0; mi < 4; ++mi)
            af[mi] = *(const bf16x8*)&As[s][aoff + (mi + 4) * 512];
        if (t + 3 < KP / BK) {
            gld16(gB0 + (t + 3) * BK, &Bs[ps][wave * 512]);
            gld16(gB1 + (t + 3) * BK, &Bs[ps][4096 + wave * 512]);
        }
        SBAR;
        WAITL; SCHEDB;
        __builtin_amdgcn_s_setprio(1);
        #pragma unroll
        for (int mi = 0; mi < 4; ++mi)
            #pragma unroll
            for (int ni = 0; ni < 4; ++ni)
                acc[mi + 4][ni] = __builtin_amdgcn_mfma_f32_16x16x32_bf16(
                    af[mi], bfr[ni], acc[mi + 4][ni], 0, 0, 0);
        __builtin_amdgcn_s_setprio(0);
        // next iteration's top WAITV+SBAR closes this tile
    }

    // ---- epilogue: C/D layout col = lane&15, row = quad*4 + reg ----
    float pv[4];
    #pragma unroll
    for (int ni = 0; ni < 4; ++ni)
        pv[ni] = pn[bn0 + wn * 64 + ni * 16 + lrow];

    #pragma unroll
    for (int mi = 0; mi < 8; ++mi) {
        #pragma unroll
        for (int r = 0; r < 4; ++r) {
            const int row = bm0 + wm * 128 + mi * 16 + quad * 4 + r;
            const float xv = xn[row];
            const size_t base = (size_t)row * C_ROWS + bn0 + wn * 64 + lrow;
            #pragma unroll
            for (int ni = 0; ni < 4; ++ni) {
                float z = fmaf(xv, pv[ni], -acc[mi][ni][r]);
                z = fmaxf(z, 1.0f + 1e-7f);
                // arccosh(z) = log(z + sqrt(z^2-1)); z >= ~26, no cancellation
                out[base + ni * 16] = -__logf(z + __fsqrt_rn(z * z - 1.0f));
            }
        }
    }
}

extern "C" void kernel_launch(void* const* d_in, const int* in_sizes, int n_in,
                              void* d_out, int out_size, void* d_ws, size_t ws_size,
                              hipStream_t stream) {
    const float* x   = (const float*)d_in[0];
    const float* pts = (const float*)d_in[1];
    float* out = (float*)d_out;

    char* ws = (char*)d_ws;
    unsigned short* Abf = (unsigned short*)ws;                                 // 16 MB
    unsigned short* Bbf = (unsigned short*)(ws + (size_t)B_ROWS * KP * 2);     // 2 MB
    float* xn = (float*)(ws + (size_t)(B_ROWS + C_ROWS) * KP * 2);             // 64 KB
    float* pn = (float*)((char*)xn + (size_t)B_ROWS * 4);                      // 8 KB
    (void)in_sizes; (void)n_in; (void)out_size; (void)ws_size;

    prep_kernel<<<(B_ROWS + C_ROWS) / 4, 256, 0, stream>>>(x, pts, Abf, Bbf, xn, pn);

    dim3 grid(B_ROWS / BM, C_ROWS / BN);
    gemm_kernel<<<grid, 512, 0, stream>>>(Abf, Bbf, xn, pn, out);
}